// Round 1
// baseline (383.024 us; speedup 1.0000x reference)
//
#include <hip/hip_runtime.h>
#include <cstdint>
#include <cstddef>

typedef unsigned short ushort_t;
typedef unsigned int uint;

typedef __attribute__((ext_vector_type(8))) short short8;   // 8 x bf16 (4 VGPRs)
typedef __attribute__((ext_vector_type(4))) float floatx4;  // 4 x f32

#define CDIM 768

// ---------- bf16 helpers (raw ushort representation) ----------
__device__ __forceinline__ float bfu(ushort_t u) {
    return __uint_as_float(((uint)u) << 16);
}
__device__ __forceinline__ void bf2(uint u, float& lo, float& hi) {
    lo = __uint_as_float(u << 16);
    hi = __uint_as_float(u & 0xffff0000u);
}
__device__ __forceinline__ ushort_t f2bfu(float f) {
    uint u = __float_as_uint(f);
    u += 0x7fffu + ((u >> 16) & 1u);   // round-to-nearest-even
    return (ushort_t)(u >> 16);
}
__device__ __forceinline__ uint pack2(float a, float b) {     // RNE pack
    return (uint)f2bfu(a) | ((uint)f2bfu(b) << 16);
}
__device__ __forceinline__ void gload_lds16(const void* g, void* l) {
    __builtin_amdgcn_global_load_lds(
        (__attribute__((address_space(1))) void*)(uintptr_t)g,
        (__attribute__((address_space(3))) void*)l, 16, 0, 0);
}

// ---------- Kernel 0a: convert Wq/Wk/Wv (fp32) -> bf16, RNE ----------
__global__ __launch_bounds__(256) void cvt_w(
    const float* __restrict__ Wq, const float* __restrict__ Wk,
    const float* __restrict__ Wv, ushort_t* __restrict__ wb)
{
    const int m = blockIdx.y;
    const float* src = (m == 0) ? Wq : (m == 1 ? Wk : Wv);
    ushort_t* dst = wb + (size_t)m * 589824;
    const int i = (blockIdx.x * 256 + threadIdx.x) * 8;
    const float4 f0 = *(const float4*)(src + i);
    const float4 f1 = *(const float4*)(src + i + 4);
    uint4 u;
    u.x = pack2(f0.x, f0.y);
    u.y = pack2(f0.z, f0.w);
    u.z = pack2(f1.x, f1.y);
    u.w = pack2(f1.z, f1.w);
    *(uint4*)(dst + i) = u;
}

// ---------- Kernel 0b: convert s1/s2 (fp32) -> bf16 activations ----------
__global__ __launch_bounds__(256) void cvt_a(
    const float* __restrict__ s1, const float* __restrict__ s2,
    ushort_t* __restrict__ ab)
{
    const int m = blockIdx.y;
    const float* src = (m == 0) ? s1 : s2;
    ushort_t* dst = ab + (size_t)m * 25165824;
    const size_t i = ((size_t)blockIdx.x * 256 + threadIdx.x) * 8;  // 12288 blocks
    const float4 f0 = *(const float4*)(src + i);
    const float4 f1 = *(const float4*)(src + i + 4);
    uint4 u;
    u.x = pack2(f0.x, f0.y);
    u.y = pack2(f0.z, f0.w);
    u.z = pack2(f1.x, f1.y);
    u.w = pack2(f1.z, f1.w);
    *(uint4*)(dst + i) = u;
}

// ---------- Kernel 1: fused QKV GEMM — 256x256 tile, 8-wave, 4-phase/K-tile,
// double-buffered LDS with counted vmcnt (T2+T3+T4+T5 per the 8-phase template).
//
// Geometry: BM=BN=256, BK=64, 8 waves (2M x 4N), per-wave C = 128x64 (acc[8][4]).
// LDS = 2 buf x (256x64 A + 256x64 B) bf16 = 128 KiB -> 1 block/CU.
// Half-tile = 128 rows x 64 k = 16 KiB = 2 gload_lds16 per thread.
// Stream of half-tiles, part order per K-tile: (B0,B1,A0,A1).
// During compute of tile t (4 phases):
//   ph0: read ALL 8 B-frags + A mt{0,1}; issue A1(t+1)  [other buffer]
//   ph1: read A mt{2..5};                issue B0(t+2)  [same buffer: B reads done ph0]
//   ph2: read A mt{6,7};                 issue B1(t+2)  [same buffer: B reads done ph0]
//   ph3: lgkmcnt(0);                     issue A0(t+2)  [same buffer: A reads drained]
//   tile boundary: vmcnt(6) (3 half-tiles in flight) + barrier -> tile t+1 resident.
// Race-freedom: every region's last ds_read completes before a barrier that
// precedes its overwriting gload_lds issue (lgkmcnt before MFMA / explicit drain).
__global__ __launch_bounds__(512, 2) void gemm_qkv(
    const ushort_t* __restrict__ ab, const ushort_t* __restrict__ wb,
    const float* __restrict__ bq, const float* __restrict__ bk, const float* __restrict__ bv,
    ushort_t* __restrict__ qo, ushort_t* __restrict__ ko, ushort_t* __restrict__ vo)
{
    const int z = blockIdx.z;
    const ushort_t* A     = ab + (size_t)(z != 0) * 25165824;
    const ushort_t* W     = wb + (size_t)z * 589824;
    const float* bias     = (z == 0) ? bq : (z == 1 ? bk : bv);
    ushort_t* out         = (z == 0) ? qo : (z == 1 ? ko : vo);

    __shared__ ushort_t At[2][256 * 64];   // 64 KB
    __shared__ ushort_t Wt[2][256 * 64];   // 64 KB

    const int tid  = threadIdx.x;
    const int wave = tid >> 6;
    const int lane = tid & 63;
    const int wm = wave >> 2, wn = wave & 3;   // 2 x 4 wave grid
    const int row0 = blockIdx.x * 256;         // token rows (b*4096+m)
    const int col0 = blockIdx.y * 256;         // output channels

    // staging: lane j covers row_off = j>>3, source chunk = (j&7) ^ (j>>3)
    // (pre-swizzled global source, linear LDS dest; all base rows are mult of 8)
    const int sro = lane >> 3;
    const int sch = ((lane & 7) ^ sro) * 8;
    const ushort_t* gA = A + (size_t)(row0 + wave * 16 + sro) * CDIM + sch;
    const ushort_t* gW = W + (size_t)(col0 + wave * 16 + sro) * CDIM + sch;

    auto stageA = [&](int half, int t) {
        const ushort_t* g = gA + (size_t)(half * 128) * CDIM + t * 64;
        ushort_t* l = &At[t & 1][(half * 128 + wave * 16) * 64];
        gload_lds16(g, l);
        gload_lds16(g + (size_t)8 * CDIM, l + 8 * 64);
    };
    auto stageB = [&](int half, int t) {
        const ushort_t* g = gW + (size_t)(half * 128) * CDIM + t * 64;
        ushort_t* l = &Wt[t & 1][(half * 128 + wave * 16) * 64];
        gload_lds16(g, l);
        gload_lds16(g + (size_t)8 * CDIM, l + 8 * 64);
    };

    floatx4 acc[8][4];
    #pragma unroll
    for (int i = 0; i < 8; ++i)
        #pragma unroll
        for (int j = 0; j < 4; ++j)
            acc[i][j] = (floatx4){0.f, 0.f, 0.f, 0.f};

    // LDS read offsets (elements). ch = (ks*4+q4) ^ (row&7); row&7 == r16&7 here.
    const int r16 = lane & 15, q4 = lane >> 4;
    const int ch0 = (q4 ^ (r16 & 7)) * 8;
    const int ch1 = ((4 + q4) ^ (r16 & 7)) * 8;
    const int aoff0 = (wm * 128 + r16) * 64 + ch0;
    const int aoff1 = (wm * 128 + r16) * 64 + ch1;
    const int boff0 = (wn * 64 + r16) * 64 + ch0;
    const int boff1 = (wn * 64 + r16) * 64 + ch1;

    // prologue: tile0 {B0,B1,A0,A1} + tile1 {B0,B1,A0}; tile0 resident, 3 in flight
    stageB(0, 0); stageB(1, 0); stageA(0, 0); stageA(1, 0);
    stageB(0, 1); stageB(1, 1); stageA(0, 1);
    asm volatile("s_waitcnt vmcnt(6)" ::: "memory");
    __builtin_amdgcn_s_barrier();

    for (int t = 0; t < 12; ++t) {
        const ushort_t* Ab = At[t & 1];
        const ushort_t* Wb = Wt[t & 1];

        // ---- phase 0: all B frags + A mt{0,1}; stage A1(t+1) ----
        short8 bfr[4][2], afA[2][2];
        #pragma unroll
        for (int nt = 0; nt < 4; ++nt) {
            bfr[nt][0] = *(const short8*)&Wb[boff0 + nt * 1024];
            bfr[nt][1] = *(const short8*)&Wb[boff1 + nt * 1024];
        }
        #pragma unroll
        for (int m2 = 0; m2 < 2; ++m2) {
            afA[m2][0] = *(const short8*)&Ab[aoff0 + m2 * 1024];
            afA[m2][1] = *(const short8*)&Ab[aoff1 + m2 * 1024];
        }
        if (t < 11) stageA(1, t + 1);
        __builtin_amdgcn_s_barrier();
        __builtin_amdgcn_s_setprio(1);
        #pragma unroll
        for (int m2 = 0; m2 < 2; ++m2)
            #pragma unroll
            for (int nt = 0; nt < 4; ++nt) {
                acc[m2][nt] = __builtin_amdgcn_mfma_f32_16x16x32_bf16(
                    afA[m2][0], bfr[nt][0], acc[m2][nt], 0, 0, 0);
                acc[m2][nt] = __builtin_amdgcn_mfma_f32_16x16x32_bf16(
                    afA[m2][1], bfr[nt][1], acc[m2][nt], 0, 0, 0);
            }
        __builtin_amdgcn_s_setprio(0);
        __builtin_amdgcn_s_barrier();

        // ---- phase 1: A mt{2..5}; stage B0(t+2) ----
        short8 afB[4][2];
        #pragma unroll
        for (int m2 = 0; m2 < 4; ++m2) {
            afB[m2][0] = *(const short8*)&Ab[aoff0 + (2 + m2) * 1024];
            afB[m2][1] = *(const short8*)&Ab[aoff1 + (2 + m2) * 1024];
        }
        if (t < 10) stageB(0, t + 2);
        __builtin_amdgcn_s_barrier();
        __builtin_amdgcn_s_setprio(1);
        #pragma unroll
        for (int m2 = 0; m2 < 2; ++m2)
            #pragma unroll
            for (int nt = 0; nt < 4; ++nt) {
                acc[2 + m2][nt] = __builtin_amdgcn_mfma_f32_16x16x32_bf16(
                    afB[m2][0], bfr[nt][0], acc[2 + m2][nt], 0, 0, 0);
                acc[2 + m2][nt] = __builtin_amdgcn_mfma_f32_16x16x32_bf16(
                    afB[m2][1], bfr[nt][1], acc[2 + m2][nt], 0, 0, 0);
            }
        __builtin_amdgcn_s_setprio(0);
        __builtin_amdgcn_s_barrier();

        // ---- phase 2: A mt{6,7}; stage B1(t+2) ----
        short8 afC[2][2];
        #pragma unroll
        for (int m2 = 0; m2 < 2; ++m2) {
            afC[m2][0] = *(const short8*)&Ab[aoff0 + (6 + m2) * 1024];
            afC[m2][1] = *(const short8*)&Ab[aoff1 + (6 + m2) * 1024];
        }
        if (t < 10) stageB(1, t + 2);
        __builtin_amdgcn_s_barrier();
        __builtin_amdgcn_s_setprio(1);
        #pragma unroll
        for (int m2 = 0; m2 < 2; ++m2)
            #pragma unroll
            for (int nt = 0; nt < 4; ++nt) {
                acc[4 + m2][nt] = __builtin_amdgcn_mfma_f32_16x16x32_bf16(
                    afB[2 + m2][0], bfr[nt][0], acc[4 + m2][nt], 0, 0, 0);
                acc[4 + m2][nt] = __builtin_amdgcn_mfma_f32_16x16x32_bf16(
                    afB[2 + m2][1], bfr[nt][1], acc[4 + m2][nt], 0, 0, 0);
            }
        __builtin_amdgcn_s_setprio(0);
        __builtin_amdgcn_s_barrier();

        // ---- phase 3: drain DS reads, then stage A0(t+2); boundary vmcnt ----
        asm volatile("s_waitcnt lgkmcnt(0)" ::: "memory");
        if (t < 10) stageA(0, t + 2);
        __builtin_amdgcn_s_barrier();
        __builtin_amdgcn_s_setprio(1);
        #pragma unroll
        for (int m2 = 0; m2 < 2; ++m2)
            #pragma unroll
            for (int nt = 0; nt < 4; ++nt) {
                acc[6 + m2][nt] = __builtin_amdgcn_mfma_f32_16x16x32_bf16(
                    afC[m2][0], bfr[nt][0], acc[6 + m2][nt], 0, 0, 0);
                acc[6 + m2][nt] = __builtin_amdgcn_mfma_f32_16x16x32_bf16(
                    afC[m2][1], bfr[nt][1], acc[6 + m2][nt], 0, 0, 0);
            }
        __builtin_amdgcn_s_setprio(0);
        if (t < 10) {
            asm volatile("s_waitcnt vmcnt(6)" ::: "memory");
        } else if (t == 10) {
            asm volatile("s_waitcnt vmcnt(0)" ::: "memory");
        }
        __builtin_amdgcn_s_barrier();
    }

    // epilogue: C/D layout col=lane&15, row=(lane>>4)*4+reg -> head-major store
    const int b = row0 >> 12;
    const int m_base = row0 & 4095;
    #pragma unroll
    for (int nt = 0; nt < 4; ++nt) {
        const int col = col0 + wn * 64 + nt * 16 + r16;
        const int h = col >> 6, d = col & 63;
        const float bb = bias[col];
        ushort_t* ob = out + ((size_t)(b * 12 + h) * 4096) * 64 + d;
        #pragma unroll
        for (int mt = 0; mt < 8; ++mt) {
            const int m = m_base + wm * 128 + mt * 16 + q4 * 4;
            #pragma unroll
            for (int r = 0; r < 4; ++r)
                ob[(size_t)(m + r) * 64] = f2bfu(acc[mt][nt][r] + bb);
        }
    }
}

// ---------- Kernel 2: adaptive avg pool over head-major q ----------
__global__ __launch_bounds__(256) void pool_agent(const ushort_t* __restrict__ q,
                                                  float* __restrict__ agent)
{
    const int a = blockIdx.x, bh = blockIdx.y;
    const int d = threadIdx.x & 63, rg = threadIdx.x >> 6;
    __shared__ float part[4][64];
    const ushort_t* p = q + ((size_t)bh * 4096 + a * 256 + rg) * 64 + d;
    float s = 0.f;
    for (int r = 0; r < 256; r += 4)
        s += bfu(p[(size_t)r * 64]);
    part[rg][d] = s;
    __syncthreads();
    if (threadIdx.x < 64) {
        const float tot = part[0][d] + part[1][d] + part[2][d] + part[3][d];
        agent[(size_t)bh * 1024 + a * 64 + d] = tot * (1.0f / 256.0f);
    }
}

// ---------- Kernel 3: stage-2 agent bias ab[h][a] (fp32) ----------
__global__ void bias_ab_k(const float* __restrict__ na, const float* __restrict__ ha,
                          const float* __restrict__ wa, float* __restrict__ ab)
{
    const int t = threadIdx.x;
    if (t >= 192) return;
    const int h = t >> 4, a = t & 15;
    const float cw[7] = {2.25f, 2.34375f, 2.28125f, 2.25f, 2.28125f, 2.34375f, 2.25f};
    float acc = 0.f;
    const float* nb = na + (h * 16 + a) * 49;
    for (int i = 0; i < 7; ++i)
        for (int j = 0; j < 7; ++j)
            acc += cw[i] * cw[j] * nb[i * 7 + j];
    acc *= (1.0f / 256.0f);
    float s = 0.f;
    for (int p = 0; p < 16; ++p)
        s += ha[(h * 16 + p) * 16 + a] + wa[(h * 16 + p) * 16 + a];
    ab[t] = acc + s * (1.0f / 16.0f);
}

// ---------- Kernel 4: stage 1 (agent -> keys/values), head-major, z-split x8 ----------
__global__ __launch_bounds__(256) void stage1(
    const ushort_t* __restrict__ k_hm, const ushort_t* __restrict__ v_hm,
    const float* __restrict__ agent, float* __restrict__ Sp, float* __restrict__ avp)
{
    const int bh = blockIdx.x, z = blockIdx.y;
    const int tid = threadIdx.x;
    __shared__ float ahs[1024];          // ah * scale, [a][d]
    __shared__ ushort_t E2[512 * 20];    // [m_local][a] bf16, row padded to 40 B

    for (int i = tid; i < 1024; i += 256)
        ahs[i] = agent[(size_t)bh * 1024 + i] * 0.125f;
    __syncthreads();

    const int m0 = z * 512;
    const ushort_t* kb = k_hm + ((size_t)bh * 4096 + m0) * 64;

    {
        const uint4* krA = (const uint4*)(kb + (size_t)tid * 64);
        const uint4* krB = (const uint4*)(kb + (size_t)(tid + 256) * 64);
        uint kuA[16], kuB[16];
        #pragma unroll
        for (int i = 0; i < 4; ++i) {
            uint4 ua = krA[i], ub = krB[i];
            kuA[i*4+0] = ua.x; kuA[i*4+1] = ua.y; kuA[i*4+2] = ua.z; kuA[i*4+3] = ua.w;
            kuB[i*4+0] = ub.x; kuB[i*4+1] = ub.y; kuB[i*4+2] = ub.z; kuB[i*4+3] = ub.w;
        }
        float dsA[16], dsB[16];
        #pragma unroll
        for (int a = 0; a < 16; ++a) { dsA[a] = 0.f; dsB[a] = 0.f; }
        #pragma unroll
        for (int c = 0; c < 16; ++c) {
            float a0, a1, a2, a3, b0, b1, b2, b3;
            bf2(kuA[2*c],   a0, a1); bf2(kuA[2*c+1], a2, a3);
            bf2(kuB[2*c],   b0, b1); bf2(kuB[2*c+1], b2, b3);
            #pragma unroll
            for (int a = 0; a < 16; ++a) {
                const floatx4 av = *(const floatx4*)&ahs[a * 64 + c * 4];
                dsA[a] += a0 * av[0] + a1 * av[1] + a2 * av[2] + a3 * av[3];
                dsB[a] += b0 * av[0] + b1 * av[1] + b2 * av[2] + b3 * av[3];
            }
        }
        uint eA[8], eB[8];
        #pragma unroll
        for (int a2 = 0; a2 < 8; ++a2) {
            eA[a2] = pack2(__expf(dsA[2*a2]), __expf(dsA[2*a2+1]));
            eB[a2] = pack2(__expf(dsB[2*a2]), __expf(dsB[2*a2+1]));
        }
        uint2* dA = (uint2*)&E2[(size_t)tid * 20];
        uint2* dB = (uint2*)&E2[(size_t)(tid + 256) * 20];
        dA[0] = make_uint2(eA[0], eA[1]); dA[1] = make_uint2(eA[2], eA[3]);
        dA[2] = make_uint2(eA[4], eA[5]); dA[3] = make_uint2(eA[6], eA[7]);
        dB[0] = make_uint2(eB[0], eB[1]); dB[1] = make_uint2(eB[2], eB[3]);
        dB[2] = make_uint2(eB[4], eB[5]); dB[3] = make_uint2(eB[6], eB[7]);
    }
    __syncthreads();

    const int d = tid & 63, g = tid >> 6;
    const ushort_t* vb = v_hm + ((size_t)bh * 4096 + m0) * 64 + d;
    float acc0 = 0, acc1 = 0, acc2 = 0, acc3 = 0;
    float ss0 = 0, ss1 = 0, ss2 = 0, ss3 = 0;
    for (int ml = 0; ml < 512; ++ml) {
        const float vv = bfu(vb[(size_t)ml * 64]);
        const uint2 ee = *(const uint2*)&E2[(size_t)ml * 20 + g * 4];
        float e0, e1, e2, e3;
        bf2(ee.x, e0, e1);
        bf2(ee.y, e2, e3);
        acc0 += e0 * vv; ss0 += e0;
        acc1 += e1 * vv; ss1 += e1;
        acc2 += e2 * vv; ss2 += e2;
        acc3 += e3 * vv; ss3 += e3;
    }
    float* avz = avp + (size_t)(z * 96 + bh) * 1024;
    avz[(g * 4 + 0) * 64 + d] = acc0;
    avz[(g * 4 + 1) * 64 + d] = acc1;
    avz[(g * 4 + 2) * 64 + d] = acc2;
    avz[(g * 4 + 3) * 64 + d] = acc3;
    if (d == 0) {
        float* Sz = Sp + (z * 96 + bh) * 16;
        Sz[g * 4 + 0] = ss0;
        Sz[g * 4 + 1] = ss1;
        Sz[g * 4 + 2] = ss2;
        Sz[g * 4 + 3] = ss3;
    }
}

// ---------- Kernel 5: stage 2 (queries -> agents) + fp32 output ----------
__global__ __launch_bounds__(256) void stage2(
    const ushort_t* __restrict__ q_hm, const float* __restrict__ avp,
    const float* __restrict__ Sp, const float* __restrict__ agent,
    const float* __restrict__ ab, float* __restrict__ out)
{
    const int nb = blockIdx.x, bh = blockIdx.y;
    const int b = bh / 12, h = bh % 12;
    const int tid = threadIdx.x;
    __shared__ float ahs[1024];
    __shared__ float avn[1024];
    __shared__ float abl[16];

    for (int i = tid; i < 1024; i += 256) {
        const int a = i >> 6;
        ahs[i] = agent[(size_t)bh * 1024 + i] * 0.125f;
        float num = 0.f, den = 0.f;
        #pragma unroll
        for (int zz = 0; zz < 8; ++zz) {
            num += avp[(size_t)(zz * 96 + bh) * 1024 + i];
            den += Sp[(zz * 96 + bh) * 16 + a];
        }
        avn[i] = num / den;
    }
    if (tid < 16) abl[tid] = ab[h * 16 + tid];
    __syncthreads();

    const int n0 = nb * 512;
    const uint4* qrA = (const uint4*)(q_hm + ((size_t)bh * 4096 + n0 + tid) * 64);
    const uint4* qrB = (const uint4*)(q_hm + ((size_t)bh * 4096 + n0 + tid + 256) * 64);
    uint quA[16], quB[16];
    #pragma unroll
    for (int i = 0; i < 4; ++i) {
        uint4 ua = qrA[i], ub = qrB[i];
        quA[i*4+0] = ua.x; quA[i*4+1] = ua.y; quA[i*4+2] = ua.z; quA[i*4+3] = ua.w;
        quB[i*4+0] = ub.x; quB[i*4+1] = ub.y; quB[i*4+2] = ub.z; quB[i*4+3] = ub.w;
    }
    float dsA[16], dsB[16];
    #pragma unroll
    for (int a = 0; a < 16; ++a) { float t = abl[a]; dsA[a] = t; dsB[a] = t; }
    #pragma unroll
    for (int c = 0; c < 16; ++c) {
        float a0, a1, a2, a3, b0, b1, b2, b3;
        bf2(quA[2*c],   a0, a1); bf2(quA[2*c+1], a2, a3);
        bf2(quB[2*c],   b0, b1); bf2(quB[2*c+1], b2, b3);
        #pragma unroll
        for (int a = 0; a < 16; ++a) {
            const floatx4 av = *(const floatx4*)&ahs[a * 64 + c * 4];
            dsA[a] += a0 * av[0] + a1 * av[1] + a2 * av[2] + a3 * av[3];
            dsB[a] += b0 * av[0] + b1 * av[1] + b2 * av[2] + b3 * av[3];
        }
    }
    float psA = 0.f, psB = 0.f;
    #pragma unroll
    for (int a = 0; a < 16; ++a) {
        dsA[a] = __expf(dsA[a]); psA += dsA[a];
        dsB[a] = __expf(dsB[a]); psB += dsB[a];
    }
    const float rA = 1.0f / psA, rB = 1.0f / psB;
    #pragma unroll
    for (int a = 0; a < 16; ++a) { dsA[a] *= rA; dsB[a] *= rB; }

    float* oA = out + ((size_t)b * 4096 + n0 + tid) * CDIM + h * 64;
    float* oB = oA + (size_t)256 * CDIM;
    #pragma unroll
    for (int dc = 0; dc < 16; ++dc) {
        floatx4 sA = {0.f, 0.f, 0.f, 0.f}, sB = {0.f, 0.f, 0.f, 0.f};
        #pragma unroll
        for (int a = 0; a < 16; ++a) {
            const floatx4 av = *(const floatx4*)&avn[a * 64 + dc * 4];
            sA += dsA[a] * av;
            sB += dsB[a] * av;
        }
        *(floatx4*)(oA + dc * 4) = sA;
        *(floatx4*)(oB + dc * 4) = sB;
    }
}

// ---------- launcher ----------
extern "C" void kernel_launch(void* const* d_in, const int* in_sizes, int n_in,
                              void* d_out, int out_size, void* d_ws, size_t ws_size,
                              hipStream_t stream) {
    (void)in_sizes; (void)n_in; (void)out_size; (void)ws_size;
    const float* s1 = (const float*)d_in[0];
    const float* s2 = (const float*)d_in[1];
    const float* Wq = (const float*)d_in[2];
    const float* bq = (const float*)d_in[3];
    const float* Wk = (const float*)d_in[4];
    const float* bk = (const float*)d_in[5];
    const float* Wv = (const float*)d_in[6];
    const float* bv = (const float*)d_in[7];
    const float* na = (const float*)d_in[9];
    const float* ha = (const float*)d_in[12];
    const float* wa = (const float*)d_in[13];
    float* out = (float*)d_out;

    char* ws = (char*)d_ws;
    ushort_t* q_hm = (ushort_t*)(ws);                 // 50,331,648 B  [96][4096][64]
    ushort_t* k_hm = (ushort_t*)(ws + 50331648);      // 50,331,648 B
    ushort_t* v_hm = (ushort_t*)(ws + 100663296);     // 50,331,648 B
    float* agent   = (float*)(ws + 150994944);        //    393,216 B  [96][16][64]
    float* Sp      = (float*)(ws + 151388160);        //     49,152 B  [8][96][16]
    float* avp     = (float*)(ws + 151437312);        //  3,145,728 B  [8][96][16][64]
    float* ab      = (float*)(ws + 154583040);        //        768 B
    ushort_t* wb   = (ushort_t*)(ws + 154583808);     //  3,538,944 B  [3][768][768]
    ushort_t* abuf = (ushort_t*)(ws + 158122752);     // 100,663,296 B [2][32768][768]

    cvt_w     <<<dim3(288, 3),    256, 0, stream>>>(Wq, Wk, Wv, wb);
    cvt_a     <<<dim3(12288, 2),  256, 0, stream>>>(s1, s2, abuf);
    gemm_qkv  <<<dim3(128, 3, 3), 512, 0, stream>>>(abuf, wb, bq, bk, bv, q_hm, k_hm, v_hm);
    pool_agent<<<dim3(16, 96),    256, 0, stream>>>(q_hm, agent);
    bias_ab_k <<<1, 256, 0, stream>>>(na, ha, wa, ab);
    stage1    <<<dim3(96, 8),     256, 0, stream>>>(k_hm, v_hm, agent, Sp, avp);
    stage2    <<<dim3(8, 96),     256, 0, stream>>>(q_hm, avp, Sp, agent, ab, out);
}

// Round 2
// 324.419 us; speedup vs baseline: 1.1806x; 1.1806x over previous
//
#include <hip/hip_runtime.h>
#include <cstdint>
#include <cstddef>

typedef unsigned short ushort_t;
typedef unsigned int uint;

typedef __attribute__((ext_vector_type(8))) short short8;   // 8 x bf16 (4 VGPRs)
typedef __attribute__((ext_vector_type(4))) float floatx4;  // 4 x f32

#define CDIM 768

// ---------- bf16 helpers (raw ushort representation) ----------
__device__ __forceinline__ float bfu(ushort_t u) {
    return __uint_as_float(((uint)u) << 16);
}
__device__ __forceinline__ void bf2(uint u, float& lo, float& hi) {
    lo = __uint_as_float(u << 16);
    hi = __uint_as_float(u & 0xffff0000u);
}
__device__ __forceinline__ ushort_t f2bfu(float f) {
    uint u = __float_as_uint(f);
    u += 0x7fffu + ((u >> 16) & 1u);   // round-to-nearest-even
    return (ushort_t)(u >> 16);
}
__device__ __forceinline__ uint pack2(float a, float b) {     // RNE pack
    return (uint)f2bfu(a) | ((uint)f2bfu(b) << 16);
}
// packed RNE f32x2 -> bf16x2 (low word = first operand), 1 VALU inst
__device__ __forceinline__ uint cvt2(float lo, float hi) {
    uint r;
    asm("v_cvt_pk_bf16_f32 %0, %1, %2" : "=v"(r) : "v"(lo), "v"(hi));
    return r;
}
__device__ __forceinline__ void gload_lds16(const void* g, void* l) {
    __builtin_amdgcn_global_load_lds(
        (__attribute__((address_space(1))) void*)(uintptr_t)g,
        (__attribute__((address_space(3))) void*)l, 16, 0, 0);
}

// ---------- Kernel 0a: convert Wq/Wk/Wv (fp32) -> bf16, RNE ----------
__global__ __launch_bounds__(256) void cvt_w(
    const float* __restrict__ Wq, const float* __restrict__ Wk,
    const float* __restrict__ Wv, ushort_t* __restrict__ wb)
{
    const int m = blockIdx.y;
    const float* src = (m == 0) ? Wq : (m == 1 ? Wk : Wv);
    ushort_t* dst = wb + (size_t)m * 589824;
    const int i = (blockIdx.x * 256 + threadIdx.x) * 8;
    const float4 f0 = *(const float4*)(src + i);
    const float4 f1 = *(const float4*)(src + i + 4);
    uint4 u;
    u.x = pack2(f0.x, f0.y);
    u.y = pack2(f0.z, f0.w);
    u.z = pack2(f1.x, f1.y);
    u.w = pack2(f1.z, f1.w);
    *(uint4*)(dst + i) = u;
}

// ---------- Kernel 0b: init agent accumulator with the q-bias ----------
// agent[bh][a][d] starts at bq[h*64+d]; gemm z==0 blocks atomically add mean(q-part).
__global__ __launch_bounds__(256) void init_agent(const float* __restrict__ bq,
                                                  float* __restrict__ agent)
{
    const int bh = blockIdx.x;          // 96
    const int h = bh % 12;
    for (int i = threadIdx.x; i < 1024; i += 256)
        agent[(size_t)bh * 1024 + i] = bq[h * 64 + (i & 63)];
}

// ---------- Kernel 1: fused QKV GEMM (round-0 structure + fused fp32->bf16
// A-staging + XCD swizzle + fused agent pooling) ----------
// A is read directly as fp32 (s1/s2), converted in-register (v_cvt_pk_bf16_f32),
// ds_write'd into the same XOR-swizzled LDS layout: At[row][c] = A[row][c^(row&7)]
// (16B chunks). Next-tile A loads are issued AFTER the second barrier so they
// overlap compute instead of being drained by the barrier's vmcnt(0).
__global__ __launch_bounds__(256, 2) void gemm_qkv(
    const float* __restrict__ s1, const float* __restrict__ s2,
    const ushort_t* __restrict__ wb,
    const float* __restrict__ bq, const float* __restrict__ bk, const float* __restrict__ bv,
    ushort_t* __restrict__ qo, ushort_t* __restrict__ ko, ushort_t* __restrict__ vo,
    float* __restrict__ agent)
{
    const int z = blockIdx.z;
    const float* A        = (z == 0) ? s1 : s2;
    const ushort_t* W     = wb + (size_t)z * 589824;
    const float* bias     = (z == 0) ? bq : (z == 1 ? bk : bv);
    ushort_t* out         = (z == 0) ? qo : (z == 1 ? ko : vo);

    __shared__ ushort_t At[128 * 64];   // 16 KB
    __shared__ ushort_t Wt[128 * 64];   // 16 KB

    const int tid  = threadIdx.x;
    const int wave = tid >> 6;
    const int lane = tid & 63;
    const int wm = wave >> 1, wn = wave & 1;

    // XCD-aware swizzle: 1536 blocks/plane, 8 XCDs, 192 blocks/chunk (bijective).
    // Within a chunk, 6 consecutive ids share one m-block (A panel) across all
    // 6 col-blocks -> A re-reads become L2 hits on that XCD.
    const int id   = blockIdx.x + (blockIdx.y << 8);   // gridDim.x = 256
    const int id2  = (id & 7) * 192 + (id >> 3);
    const int row0 = (id2 / 6) * 128;   // token rows (b*4096+m)
    const int col0 = (id2 % 6) * 128;   // output channels

    // staging geometry: lane j covers row_off = j>>3, source chunk = (j&7) ^ (j>>3)
    const int sro = lane >> 3;
    const int sch = ((lane & 7) ^ sro) * 8;
    const float*    gaF = A + (size_t)(row0 + wave * 32 + sro) * CDIM + sch;
    const ushort_t* gwB = W + (size_t)(col0 + wave * 32 + sro) * CDIM + sch;

    floatx4 acc[4][4];
    #pragma unroll
    for (int i = 0; i < 4; ++i)
        #pragma unroll
        for (int j = 0; j < 4; ++j)
            acc[i][j] = (floatx4){0.f, 0.f, 0.f, 0.f};

    const int q4 = lane >> 4, r16 = lane & 15;

    // prefetch A (fp32) for kt = 0
    float4 ra[4][2];
    #pragma unroll
    for (int i = 0; i < 4; ++i) {
        const float* p = gaF + (size_t)i * 8 * CDIM;
        ra[i][0] = *(const float4*)(p);
        ra[i][1] = *(const float4*)(p + 4);
    }

    for (int kt = 0; kt < CDIM; kt += 64) {
        __syncthreads();
        #pragma unroll
        for (int i = 0; i < 4; ++i)
            gload_lds16(gwB + (size_t)i * 8 * CDIM + kt, &Wt[(wave * 32 + i * 8) * 64]);
        #pragma unroll
        for (int i = 0; i < 4; ++i) {
            uint4 u;
            u.x = cvt2(ra[i][0].x, ra[i][0].y);
            u.y = cvt2(ra[i][0].z, ra[i][0].w);
            u.z = cvt2(ra[i][1].x, ra[i][1].y);
            u.w = cvt2(ra[i][1].z, ra[i][1].w);
            // dest chunk = lane&7; holds source chunk (lane&7)^sro  ==  c^(row&7)
            *(uint4*)&At[(wave * 32 + i * 8 + sro) * 64 + (lane & 7) * 8] = u;
        }
        __syncthreads();
        // issue next tile's A loads AFTER the barrier -> they fly during compute
        if (kt + 64 < CDIM) {
            #pragma unroll
            for (int i = 0; i < 4; ++i) {
                const float* p = gaF + (size_t)i * 8 * CDIM + kt + 64;
                ra[i][0] = *(const float4*)(p);
                ra[i][1] = *(const float4*)(p + 4);
            }
        }
        #pragma unroll
        for (int ks = 0; ks < 2; ++ks) {
            short8 af[4], bfr[4];
            #pragma unroll
            for (int mt = 0; mt < 4; ++mt) {
                const int row = wm * 64 + mt * 16 + r16;
                const int ch  = (ks * 4 + q4) ^ (row & 7);
                af[mt] = *(const short8*)&At[row * 64 + ch * 8];
            }
            #pragma unroll
            for (int nt = 0; nt < 4; ++nt) {
                const int row = wn * 64 + nt * 16 + r16;
                const int ch  = (ks * 4 + q4) ^ (row & 7);
                bfr[nt] = *(const short8*)&Wt[row * 64 + ch * 8];
            }
            #pragma unroll
            for (int mt = 0; mt < 4; ++mt)
                #pragma unroll
                for (int nt = 0; nt < 4; ++nt)
                    acc[mt][nt] = __builtin_amdgcn_mfma_f32_16x16x32_bf16(
                        af[mt], bfr[nt], acc[mt][nt], 0, 0, 0);
        }
    }

    // epilogue: C/D layout col=lane&15, row=(lane>>4)*4+reg -> head-major store.
    // For z==0 additionally fold the adaptive-avg-pool: the block's 128 rows lie
    // in exactly one agent chunk (m_base>>8); sum acc over (mt,r), reduce over q4
    // lanes, one atomicAdd per col per wave.
    const int b = row0 >> 12;
    const int m_base = row0 & 4095;
    #pragma unroll
    for (int nt = 0; nt < 4; ++nt) {
        const int col = col0 + wn * 64 + nt * 16 + r16;
        const int h = col >> 6, d = col & 63;
        const float bb = bias[col];
        ushort_t* ob = out + ((size_t)(b * 12 + h) * 4096) * 64 + d;
        float psum = 0.f;
        #pragma unroll
        for (int mt = 0; mt < 4; ++mt) {
            const int m = m_base + wm * 64 + mt * 16 + q4 * 4;
            #pragma unroll
            for (int r = 0; r < 4; ++r) {
                ob[(size_t)(m + r) * 64] = f2bfu(acc[mt][nt][r] + bb);
                psum += acc[mt][nt][r];
            }
        }
        if (z == 0) {
            psum += __shfl_xor(psum, 16);
            psum += __shfl_xor(psum, 32);
            if (q4 == 0)
                atomicAdd(&agent[(size_t)(b * 12 + h) * 1024 + (m_base >> 8) * 64 + d],
                          psum * (1.0f / 256.0f));
        }
    }
}

// ---------- Kernel 3: stage-2 agent bias ab[h][a] (fp32) ----------
__global__ void bias_ab_k(const float* __restrict__ na, const float* __restrict__ ha,
                          const float* __restrict__ wa, float* __restrict__ ab)
{
    const int t = threadIdx.x;
    if (t >= 192) return;
    const int h = t >> 4, a = t & 15;
    const float cw[7] = {2.25f, 2.34375f, 2.28125f, 2.25f, 2.28125f, 2.34375f, 2.25f};
    float acc = 0.f;
    const float* nb = na + (h * 16 + a) * 49;
    for (int i = 0; i < 7; ++i)
        for (int j = 0; j < 7; ++j)
            acc += cw[i] * cw[j] * nb[i * 7 + j];
    acc *= (1.0f / 256.0f);
    float s = 0.f;
    for (int p = 0; p < 16; ++p)
        s += ha[(h * 16 + p) * 16 + a] + wa[(h * 16 + p) * 16 + a];
    ab[t] = acc + s * (1.0f / 16.0f);
}

// ---------- Kernel 4: stage 1 (agent -> keys/values), head-major, z-split x8 ----------
__global__ __launch_bounds__(256) void stage1(
    const ushort_t* __restrict__ k_hm, const ushort_t* __restrict__ v_hm,
    const float* __restrict__ agent, float* __restrict__ Sp, float* __restrict__ avp)
{
    const int bh = blockIdx.x, z = blockIdx.y;
    const int tid = threadIdx.x;
    __shared__ float ahs[1024];          // ah * scale, [a][d]
    __shared__ ushort_t E2[512 * 20];    // [m_local][a] bf16, row padded to 40 B

    for (int i = tid; i < 1024; i += 256)
        ahs[i] = agent[(size_t)bh * 1024 + i] * 0.125f;
    __syncthreads();

    const int m0 = z * 512;
    const ushort_t* kb = k_hm + ((size_t)bh * 4096 + m0) * 64;

    {
        const uint4* krA = (const uint4*)(kb + (size_t)tid * 64);
        const uint4* krB = (const uint4*)(kb + (size_t)(tid + 256) * 64);
        uint kuA[16], kuB[16];
        #pragma unroll
        for (int i = 0; i < 4; ++i) {
            uint4 ua = krA[i], ub = krB[i];
            kuA[i*4+0] = ua.x; kuA[i*4+1] = ua.y; kuA[i*4+2] = ua.z; kuA[i*4+3] = ua.w;
            kuB[i*4+0] = ub.x; kuB[i*4+1] = ub.y; kuB[i*4+2] = ub.z; kuB[i*4+3] = ub.w;
        }
        float dsA[16], dsB[16];
        #pragma unroll
        for (int a = 0; a < 16; ++a) { dsA[a] = 0.f; dsB[a] = 0.f; }
        #pragma unroll
        for (int c = 0; c < 16; ++c) {
            float a0, a1, a2, a3, b0, b1, b2, b3;
            bf2(kuA[2*c],   a0, a1); bf2(kuA[2*c+1], a2, a3);
            bf2(kuB[2*c],   b0, b1); bf2(kuB[2*c+1], b2, b3);
            #pragma unroll
            for (int a = 0; a < 16; ++a) {
                const floatx4 av = *(const floatx4*)&ahs[a * 64 + c * 4];
                dsA[a] += a0 * av[0] + a1 * av[1] + a2 * av[2] + a3 * av[3];
                dsB[a] += b0 * av[0] + b1 * av[1] + b2 * av[2] + b3 * av[3];
            }
        }
        uint eA[8], eB[8];
        #pragma unroll
        for (int a2 = 0; a2 < 8; ++a2) {
            eA[a2] = pack2(__expf(dsA[2*a2]), __expf(dsA[2*a2+1]));
            eB[a2] = pack2(__expf(dsB[2*a2]), __expf(dsB[2*a2+1]));
        }
        uint2* dA = (uint2*)&E2[(size_t)tid * 20];
        uint2* dB = (uint2*)&E2[(size_t)(tid + 256) * 20];
        dA[0] = make_uint2(eA[0], eA[1]); dA[1] = make_uint2(eA[2], eA[3]);
        dA[2] = make_uint2(eA[4], eA[5]); dA[3] = make_uint2(eA[6], eA[7]);
        dB[0] = make_uint2(eB[0], eB[1]); dB[1] = make_uint2(eB[2], eB[3]);
        dB[2] = make_uint2(eB[4], eB[5]); dB[3] = make_uint2(eB[6], eB[7]);
    }
    __syncthreads();

    const int d = tid & 63, g = tid >> 6;
    const ushort_t* vb = v_hm + ((size_t)bh * 4096 + m0) * 64 + d;
    float acc0 = 0, acc1 = 0, acc2 = 0, acc3 = 0;
    float ss0 = 0, ss1 = 0, ss2 = 0, ss3 = 0;
    for (int ml = 0; ml < 512; ++ml) {
        const float vv = bfu(vb[(size_t)ml * 64]);
        const uint2 ee = *(const uint2*)&E2[(size_t)ml * 20 + g * 4];
        float e0, e1, e2, e3;
        bf2(ee.x, e0, e1);
        bf2(ee.y, e2, e3);
        acc0 += e0 * vv; ss0 += e0;
        acc1 += e1 * vv; ss1 += e1;
        acc2 += e2 * vv; ss2 += e2;
        acc3 += e3 * vv; ss3 += e3;
    }
    float* avz = avp + (size_t)(z * 96 + bh) * 1024;
    avz[(g * 4 + 0) * 64 + d] = acc0;
    avz[(g * 4 + 1) * 64 + d] = acc1;
    avz[(g * 4 + 2) * 64 + d] = acc2;
    avz[(g * 4 + 3) * 64 + d] = acc3;
    if (d == 0) {
        float* Sz = Sp + (z * 96 + bh) * 16;
        Sz[g * 4 + 0] = ss0;
        Sz[g * 4 + 1] = ss1;
        Sz[g * 4 + 2] = ss2;
        Sz[g * 4 + 3] = ss3;
    }
}

// ---------- Kernel 5: stage 2 (queries -> agents) + fp32 output ----------
__global__ __launch_bounds__(256) void stage2(
    const ushort_t* __restrict__ q_hm, const float* __restrict__ avp,
    const float* __restrict__ Sp, const float* __restrict__ agent,
    const float* __restrict__ ab, float* __restrict__ out)
{
    const int nb = blockIdx.x, bh = blockIdx.y;
    const int b = bh / 12, h = bh % 12;
    const int tid = threadIdx.x;
    __shared__ float ahs[1024];
    __shared__ float avn[1024];
    __shared__ float abl[16];

    for (int i = tid; i < 1024; i += 256) {
        const int a = i >> 6;
        ahs[i] = agent[(size_t)bh * 1024 + i] * 0.125f;
        float num = 0.f, den = 0.f;
        #pragma unroll
        for (int zz = 0; zz < 8; ++zz) {
            num += avp[(size_t)(zz * 96 + bh) * 1024 + i];
            den += Sp[(zz * 96 + bh) * 16 + a];
        }
        avn[i] = num / den;
    }
    if (tid < 16) abl[tid] = ab[h * 16 + tid];
    __syncthreads();

    const int n0 = nb * 512;
    const uint4* qrA = (const uint4*)(q_hm + ((size_t)bh * 4096 + n0 + tid) * 64);
    const uint4* qrB = (const uint4*)(q_hm + ((size_t)bh * 4096 + n0 + tid + 256) * 64);
    uint quA[16], quB[16];
    #pragma unroll
    for (int i = 0; i < 4; ++i) {
        uint4 ua = qrA[i], ub = qrB[i];
        quA[i*4+0] = ua.x; quA[i*4+1] = ua.y; quA[i*4+2] = ua.z; quA[i*4+3] = ua.w;
        quB[i*4+0] = ub.x; quB[i*4+1] = ub.y; quB[i*4+2] = ub.z; quB[i*4+3] = ub.w;
    }
    float dsA[16], dsB[16];
    #pragma unroll
    for (int a = 0; a < 16; ++a) { float t = abl[a]; dsA[a] = t; dsB[a] = t; }
    #pragma unroll
    for (int c = 0; c < 16; ++c) {
        float a0, a1, a2, a3, b0, b1, b2, b3;
        bf2(quA[2*c],   a0, a1); bf2(quA[2*c+1], a2, a3);
        bf2(quB[2*c],   b0, b1); bf2(quB[2*c+1], b2, b3);
        #pragma unroll
        for (int a = 0; a < 16; ++a) {
            const floatx4 av = *(const floatx4*)&ahs[a * 64 + c * 4];
            dsA[a] += a0 * av[0] + a1 * av[1] + a2 * av[2] + a3 * av[3];
            dsB[a] += b0 * av[0] + b1 * av[1] + b2 * av[2] + b3 * av[3];
        }
    }
    float psA = 0.f, psB = 0.f;
    #pragma unroll
    for (int a = 0; a < 16; ++a) {
        dsA[a] = __expf(dsA[a]); psA += dsA[a];
        dsB[a] = __expf(dsB[a]); psB += dsB[a];
    }
    const float rA = 1.0f / psA, rB = 1.0f / psB;
    #pragma unroll
    for (int a = 0; a < 16; ++a) { dsA[a] *= rA; dsB[a] *= rB; }

    float* oA = out + ((size_t)b * 4096 + n0 + tid) * CDIM + h * 64;
    float* oB = oA + (size_t)256 * CDIM;
    #pragma unroll
    for (int dc = 0; dc < 16; ++dc) {
        floatx4 sA = {0.f, 0.f, 0.f, 0.f}, sB = {0.f, 0.f, 0.f, 0.f};
        #pragma unroll
        for (int a = 0; a < 16; ++a) {
            const floatx4 av = *(const floatx4*)&avn[a * 64 + dc * 4];
            sA += dsA[a] * av;
            sB += dsB[a] * av;
        }
        *(floatx4*)(oA + dc * 4) = sA;
        *(floatx4*)(oB + dc * 4) = sB;
    }
}

// ---------- launcher ----------
extern "C" void kernel_launch(void* const* d_in, const int* in_sizes, int n_in,
                              void* d_out, int out_size, void* d_ws, size_t ws_size,
                              hipStream_t stream) {
    (void)in_sizes; (void)n_in; (void)out_size; (void)ws_size;
    const float* s1 = (const float*)d_in[0];
    const float* s2 = (const float*)d_in[1];
    const float* Wq = (const float*)d_in[2];
    const float* bq = (const float*)d_in[3];
    const float* Wk = (const float*)d_in[4];
    const float* bk = (const float*)d_in[5];
    const float* Wv = (const float*)d_in[6];
    const float* bv = (const float*)d_in[7];
    const float* na = (const float*)d_in[9];
    const float* ha = (const float*)d_in[12];
    const float* wa = (const float*)d_in[13];
    float* out = (float*)d_out;

    char* ws = (char*)d_ws;
    ushort_t* q_hm = (ushort_t*)(ws);                 // 50,331,648 B  [96][4096][64]
    ushort_t* k_hm = (ushort_t*)(ws + 50331648);      // 50,331,648 B
    ushort_t* v_hm = (ushort_t*)(ws + 100663296);     // 50,331,648 B
    float* agent   = (float*)(ws + 150994944);        //    393,216 B  [96][16][64]
    float* Sp      = (float*)(ws + 151388160);        //     49,152 B  [8][96][16]
    float* avp     = (float*)(ws + 151437312);        //  3,145,728 B  [8][96][16][64]
    float* ab      = (float*)(ws + 154583040);        //        768 B
    ushort_t* wb   = (ushort_t*)(ws + 154583808);     //  3,538,944 B  [3][768][768]

    cvt_w      <<<dim3(288, 3),    256, 0, stream>>>(Wq, Wk, Wv, wb);
    init_agent <<<dim3(96),        256, 0, stream>>>(bq, agent);
    gemm_qkv   <<<dim3(256, 6, 3), 256, 0, stream>>>(s1, s2, wb, bq, bk, bv,
                                                     q_hm, k_hm, v_hm, agent);
    bias_ab_k  <<<1, 256, 0, stream>>>(na, ha, wa, ab);
    stage1     <<<dim3(96, 8),     256, 0, stream>>>(k_hm, v_hm, agent, Sp, avp);
    stage2     <<<dim3(8, 96),     256, 0, stream>>>(q_hm, avp, Sp, agent, ab, out);
}